// Round 8
// baseline (515.185 us; speedup 1.0000x reference)
//
#include <hip/hip_runtime.h>
#include <math.h>

#define NEG_SLOPE 0.2f
#define LOG2E 1.44269504088896340736f

#if __has_builtin(__builtin_amdgcn_exp2f)
#define EXP2(x) __builtin_amdgcn_exp2f(x)
#else
#define EXP2(x) exp2f(x)
#endif

// in-wave butterfly add via DPP (plain VALU, no DS pipe): validated R5-R7.
#define DPP_ADD(p, ctrl) \
    p += __int_as_float(__builtin_amdgcn_update_dpp(0, __float_as_int(p), ctrl, 0xf, 0xf, true))

// ---------------------------------------------------------------------------
// AtomEncoder + edge histogram (fused).
// ---------------------------------------------------------------------------
__global__ __launch_bounds__(256) void embed_kernel(
        const int* __restrict__ feat, const float* __restrict__ emb,
        const int* __restrict__ dstE, int* __restrict__ counts,
        float* __restrict__ x, int N, int E) {
    int gid = blockIdx.x * 256 + threadIdx.x;
    if (gid < E) atomicAdd(&counts[dstE[gid]], 1);

    const int offs[9] = {0, 119, 124, 136, 148, 158, 164, 170, 172};
    int sub  = threadIdx.x >> 6;
    int lane = threadIdx.x & 63;
    int n = __builtin_amdgcn_readfirstlane(blockIdx.x * 4 + sub);
    if (n >= N) return;
    float s = 0.f;
#pragma unroll
    for (int j = 0; j < 9; ++j) {
        int idx = feat[n * 9 + j] + offs[j];
        s += emb[idx * 64 + lane];
    }
    x[(size_t)n * 64 + lane] = s;
}

// ---------------------------------------------------------------------------
// Dual GEMM v3: tile 128x128, 256 threads, 8x8 register block per thread in
// SPLIT 4+4 form: cols {cg*4..+3, 64+cg*4..+3}, rows {rg*4..+3, 64+rg*4..+3}.
// All four LDS compute reads are 2-way bank-aliased (free) vs the 4-way
// conflict of the contiguous-8 layout. BK=32, two K-phases, 32 KB LDS.
// ---------------------------------------------------------------------------
__global__ __launch_bounds__(256) void gemm_kernel(
        const float* __restrict__ x,
        const float* __restrict__ Wl, const float* __restrict__ Wr,
        const float* __restrict__ bl, const float* __restrict__ br,
        float* __restrict__ xl, float* __restrict__ xr, int N) {
    __shared__ __align__(16) float As[32][128];   // [k][m] 16 KB
    __shared__ __align__(16) float Bs[32][128];   // [k][c] 16 KB
    int t  = threadIdx.x;
    int m0 = blockIdx.x * 128;
    int ct = blockIdx.y;  // 0,1 -> Wl ; 2,3 -> Wr
    const float* B    = (ct < 2) ? Wl : Wr;
    const float* bias = (ct < 2) ? bl : br;
    float*       out  = (ct < 2) ? xl : xr;
    int cb = (ct & 1) * 128;

    int lrow = t >> 1;        // A-load: row within tile (0..127)
    int lq0  = (t & 1) * 4;   // A-load: first k-quad of this phase (0 or 4)
    int c4   = t & 31;        // B-load: col quad
    int k0   = t >> 5;        // B-load: k row 0..7
    int rg   = t >> 4;        // compute: row group 0..15 -> rows rg*4, 64+rg*4
    int cg   = t & 15;        // compute: col group 0..15 -> cols cg*4, 64+cg*4

    float4 acc[16];           // acc[r*2+h]: r=0..3 rows rg*4+r ; r=4..7 rows 64+rg*4+(r-4)
#pragma unroll
    for (int i = 0; i < 16; ++i) acc[i] = make_float4(0.f, 0.f, 0.f, 0.f);

    int arow = m0 + lrow;
#pragma unroll
    for (int kb = 0; kb < 2; ++kb) {
        float4 av[4];
#pragma unroll
        for (int j = 0; j < 4; ++j) {
            av[j] = make_float4(0.f, 0.f, 0.f, 0.f);
            if (arow < N)
                av[j] = *(const float4*)(x + (size_t)arow * 64 + kb * 32 + (lq0 + j) * 4);
        }
        float4 bv[4];
#pragma unroll
        for (int j = 0; j < 4; ++j)
            bv[j] = *(const float4*)(B + (size_t)(kb * 32 + k0 + j * 8) * 256 + cb + c4 * 4);

        if (kb) __syncthreads();   // previous phase fully consumed
#pragma unroll
        for (int j = 0; j < 4; ++j) {
            int kq = lq0 + j;
            As[kq * 4 + 0][lrow] = av[j].x;
            As[kq * 4 + 1][lrow] = av[j].y;
            As[kq * 4 + 2][lrow] = av[j].z;
            As[kq * 4 + 3][lrow] = av[j].w;
        }
#pragma unroll
        for (int j = 0; j < 4; ++j)
            *(float4*)(&Bs[k0 + j * 8][c4 * 4]) = bv[j];
        __syncthreads();

#pragma unroll 2
        for (int k = 0; k < 32; ++k) {
            float4 b0 = *(const float4*)(&Bs[k][cg * 4]);        // banks 4cg..+3: 2-way, free
            float4 b1 = *(const float4*)(&Bs[k][cg * 4 + 64]);
            float4 a0 = *(const float4*)(&As[k][rg * 4]);        // 16-lane broadcast groups
            float4 a1 = *(const float4*)(&As[k][rg * 4 + 64]);
            float ar[8] = {a0.x, a0.y, a0.z, a0.w, a1.x, a1.y, a1.z, a1.w};
#pragma unroll
            for (int r = 0; r < 8; ++r) {
                acc[r * 2].x     += ar[r] * b0.x; acc[r * 2].y     += ar[r] * b0.y;
                acc[r * 2].z     += ar[r] * b0.z; acc[r * 2].w     += ar[r] * b0.w;
                acc[r * 2 + 1].x += ar[r] * b1.x; acc[r * 2 + 1].y += ar[r] * b1.y;
                acc[r * 2 + 1].z += ar[r] * b1.z; acc[r * 2 + 1].w += ar[r] * b1.w;
            }
        }
    }

    float4 bb0 = *(const float4*)(bias + cb + cg * 4);
    float4 bb1 = *(const float4*)(bias + cb + cg * 4 + 64);
#pragma unroll
    for (int r = 0; r < 8; ++r) {
        int row = m0 + ((r < 4) ? rg * 4 + r : 64 + rg * 4 + (r - 4));
        if (row < N) {
            float4 o0 = acc[r * 2], o1 = acc[r * 2 + 1];
            o0.x += bb0.x; o0.y += bb0.y; o0.z += bb0.z; o0.w += bb0.w;
            o1.x += bb1.x; o1.y += bb1.y; o1.z += bb1.z; o1.w += bb1.w;
            *(float4*)(out + (size_t)row * 256 + cb + cg * 4)      = o0;
            *(float4*)(out + (size_t)row * 256 + cb + cg * 4 + 64) = o1;
        }
    }
}

// ---------------------------------------------------------------------------
// CSR build (self loop at each segment head, +1 folded into scan).
// blockSums stays RAW per-1024-chunk sums; finalize computes its (block-
// constant) prefix with one in-wave reduction -> scan_sums dispatch removed.
// ---------------------------------------------------------------------------
__global__ void scan_block_kernel(const int* __restrict__ counts, int* __restrict__ excl,
                                  int* __restrict__ blockSums, int N) {
    __shared__ int lds[256];
    int b = blockIdx.x, t = threadIdx.x;
    int base = b * 1024 + t * 4;
    int v0 = (base + 0 < N) ? counts[base + 0] + 1 : 0;
    int v1 = (base + 1 < N) ? counts[base + 1] + 1 : 0;
    int v2 = (base + 2 < N) ? counts[base + 2] + 1 : 0;
    int v3 = (base + 3 < N) ? counts[base + 3] + 1 : 0;
    int s = v0 + v1 + v2 + v3;
    lds[t] = s;
    __syncthreads();
    for (int off = 1; off < 256; off <<= 1) {
        int add = (t >= off) ? lds[t - off] : 0;
        __syncthreads();
        lds[t] += add;
        __syncthreads();
    }
    int run = lds[t] - s;
    if (base + 0 < N) excl[base + 0] = run; run += v0;
    if (base + 1 < N) excl[base + 1] = run; run += v1;
    if (base + 2 < N) excl[base + 2] = run; run += v2;
    if (base + 3 < N) excl[base + 3] = run;
    if (t == 255) blockSums[b] = lds[255];
}

__global__ void finalize_kernel(int* __restrict__ csr_off, const int* __restrict__ blockSums,
                                int* __restrict__ cursor, int* __restrict__ csr_src,
                                int N, int total) {
    __shared__ int s_pref;
    int b = (blockIdx.x * 256) >> 10;   // block-constant chunk index
    if (threadIdx.x < 64) {
        int v = (threadIdx.x < b) ? blockSums[threadIdx.x] : 0;  // nb <= 64
        v += __shfl_xor(v, 1);  v += __shfl_xor(v, 2);
        v += __shfl_xor(v, 4);  v += __shfl_xor(v, 8);
        v += __shfl_xor(v, 16); v += __shfl_xor(v, 32);
        if (threadIdx.x == 0) s_pref = v;
    }
    __syncthreads();
    int S = s_pref;
    int i = blockIdx.x * 256 + threadIdx.x;
    if (i < N) {
        int v = csr_off[i] + S;
        csr_off[i] = v;
        csr_src[v] = i;    // self loop at segment head
        cursor[i]  = v + 1;
    }
    if (i == 0) csr_off[N] = total;
}

__global__ void scatter_kernel(const int* __restrict__ src, const int* __restrict__ dst,
                               int* __restrict__ cursor, int* __restrict__ csr_src, int E) {
    int e = blockIdx.x * 256 + threadIdx.x;
    if (e < E) {
        int pos = atomicAdd(&cursor[dst[e]], 1);
        csr_src[pos] = src[e];
    }
}

// ---------------------------------------------------------------------------
// GATv2 aggregation (R7 best: 3-buffer rotating pipeline, DPP reduction).
// At the L2-miss-path ceiling (~3.5 TB/s on 238 MB of L2 misses) -- unchanged.
// ---------------------------------------------------------------------------
__global__ __launch_bounds__(256) void agg_kernel(
        const float* __restrict__ xl, const float* __restrict__ xr,
        const int* __restrict__ csr_off, const int* __restrict__ csr_src,
        const float* __restrict__ att,   // [4*64] this layer
        const float* __restrict__ gbias, // [64] this layer
        float* __restrict__ xout, int N, int apply_gelu) {
    int wave = threadIdx.x >> 6;
    int lane = threadIdx.x & 63;
    int n = __builtin_amdgcn_readfirstlane(blockIdx.x * 4 + wave);
    if (n >= N) return;

    float4 att4 = ((const float4*)att)[lane];
    att4.x *= LOG2E; att4.y *= LOG2E; att4.z *= LOG2E; att4.w *= LOG2E;
    float4 xr4 = *(const float4*)(xr + (size_t)n * 256 + lane * 4);

    int beg  = csr_off[n];       // uniform -> s_load
    int end  = csr_off[n + 1];
    int m    = end - beg;        // includes self loop, >= 1
    int last = end - 1;

    const float* __restrict__ xlp = xl + lane * 4;

    auto idx4 = [&](int pos) -> int4 {
        int4 v;
        v.x = csr_src[min(pos,     last)];
        v.y = csr_src[min(pos + 1, last)];
        v.z = csr_src[min(pos + 2, last)];
        v.w = csr_src[min(pos + 3, last)];
        return v;
    };
    auto rows4 = [&](const int4& iv, float4& r0, float4& r1, float4& r2, float4& r3) {
        r0 = *(const float4*)(xlp + (size_t)iv.x * 256);
        r1 = *(const float4*)(xlp + (size_t)iv.y * 256);
        r2 = *(const float4*)(xlp + (size_t)iv.z * 256);
        r3 = *(const float4*)(xlp + (size_t)iv.w * 256);
    };
    auto logit = [&](const float4& v) -> float {
        float s0 = v.x + xr4.x, s1 = v.y + xr4.y, s2 = v.z + xr4.z, s3 = v.w + xr4.w;
        float t0 = fmaxf(s0, NEG_SLOPE * s0);
        float t1 = fmaxf(s1, NEG_SLOPE * s1);
        float t2 = fmaxf(s2, NEG_SLOPE * s2);
        float t3 = fmaxf(s3, NEG_SLOPE * s3);
        return t0 * att4.x + t1 * att4.y + t2 * att4.z + t3 * att4.w;
    };

    float ax = 0.f, ay = 0.f, az = 0.f, aw = 0.f, denom = 0.f;

    auto compute4 = [&](const float4& e0, const float4& e1, const float4& e2,
                        const float4& e3, int kbase) {
        float p0 = logit(e0), p1 = logit(e1), p2 = logit(e2), p3 = logit(e3);
        DPP_ADD(p0, 0xB1);  DPP_ADD(p1, 0xB1);  DPP_ADD(p2, 0xB1);  DPP_ADD(p3, 0xB1);
        DPP_ADD(p0, 0x4E);  DPP_ADD(p1, 0x4E);  DPP_ADD(p2, 0x4E);  DPP_ADD(p3, 0x4E);
        DPP_ADD(p0, 0x141); DPP_ADD(p1, 0x141); DPP_ADD(p2, 0x141); DPP_ADD(p3, 0x141);
        DPP_ADD(p0, 0x140); DPP_ADD(p1, 0x140); DPP_ADD(p2, 0x140); DPP_ADD(p3, 0x140);
        float w0 = EXP2(p0);
        float w1 = (kbase + 1 < m) ? EXP2(p1) : 0.f;
        float w2 = (kbase + 2 < m) ? EXP2(p2) : 0.f;
        float w3 = (kbase + 3 < m) ? EXP2(p3) : 0.f;
        denom += (w0 + w1) + (w2 + w3);
        ax += w0 * e0.x + w1 * e1.x + w2 * e2.x + w3 * e3.x;
        ay += w0 * e0.y + w1 * e1.y + w2 * e2.y + w3 * e3.y;
        az += w0 * e0.z + w1 * e1.z + w2 * e2.z + w3 * e3.z;
        aw += w0 * e0.w + w1 * e1.w + w2 * e2.w + w3 * e3.w;
    };

    float4 a0, a1, a2, a3, b0, b1, b2, b3, c0, c1, c2, c3;
    rows4(idx4(beg),     a0, a1, a2, a3);
    rows4(idx4(beg + 4), b0, b1, b2, b3);
    rows4(idx4(beg + 8), c0, c1, c2, c3);
    int4 ja = idx4(beg + 12);
    int4 jb = idx4(beg + 16);
    int4 jc = idx4(beg + 20);

    int g = 0;
    while (true) {
        compute4(a0, a1, a2, a3, g);
        if (g + 4 >= m) break;
        rows4(ja, a0, a1, a2, a3);  ja = idx4(beg + g + 24);

        compute4(b0, b1, b2, b3, g + 4);
        if (g + 8 >= m) break;
        rows4(jb, b0, b1, b2, b3);  jb = idx4(beg + g + 28);

        compute4(c0, c1, c2, c3, g + 8);
        if (g + 12 >= m) break;
        rows4(jc, c0, c1, c2, c3);  jc = idx4(beg + g + 32);

        g += 12;
    }

    float inv = 1.f / denom;
    float rx = ax * inv, ry = ay * inv, rz = az * inv, rw = aw * inv;
    rx += __shfl_xor(rx, 16); rx += __shfl_xor(rx, 32);
    ry += __shfl_xor(ry, 16); ry += __shfl_xor(ry, 32);
    rz += __shfl_xor(rz, 16); rz += __shfl_xor(rz, 32);
    rw += __shfl_xor(rw, 16); rw += __shfl_xor(rw, 32);

    if (lane < 16) {
        int d0 = lane * 4;
        float4 bv = *(const float4*)(gbias + d0);
        float ox = 0.25f * rx + bv.x;
        float oy = 0.25f * ry + bv.y;
        float oz = 0.25f * rz + bv.z;
        float ow = 0.25f * rw + bv.w;
        if (apply_gelu) {
            const float kk = 0.70710678118654752440f;
            ox = 0.5f * ox * (1.f + erff(ox * kk));
            oy = 0.5f * oy * (1.f + erff(oy * kk));
            oz = 0.5f * oz * (1.f + erff(oz * kk));
            ow = 0.5f * ow * (1.f + erff(ow * kk));
        }
        *(float4*)(xout + (size_t)n * 64 + d0) = make_float4(ox, oy, oz, ow);
    }
}

// ---------------------------------------------------------------------------
// Global mean pool (batch sorted) + classifier. Block per graph, 256 threads.
// ---------------------------------------------------------------------------
__global__ __launch_bounds__(256) void pool_kernel(
        const float* __restrict__ x, const int* __restrict__ batch,
        const float* __restrict__ Wc, const float* __restrict__ bc,
        float* __restrict__ out, int N, int G) {
    __shared__ float part[4][64];
    __shared__ float pooled[64];
    int g = blockIdx.x, t = threadIdx.x;
    int sub = t >> 6, lane = t & 63;
    int lo = 0, hi = N;
    while (lo < hi) { int mid = (lo + hi) >> 1; if (batch[mid] < g) lo = mid + 1; else hi = mid; }
    int beg = lo;
    hi = N;
    while (lo < hi) { int mid = (lo + hi) >> 1; if (batch[mid] < g + 1) lo = mid + 1; else hi = mid; }
    int end = lo;

    float acc = 0.f;
    for (int n = beg + sub; n < end; n += 4) acc += x[(size_t)n * 64 + lane];
    part[sub][lane] = acc;
    __syncthreads();
    if (t < 64) {
        float s = (part[0][t] + part[1][t]) + (part[2][t] + part[3][t]);
        int cnt = end - beg;
        pooled[t] = (cnt > 0) ? s / (float)cnt : 0.f;
    }
    __syncthreads();
    if (t < 10) {
        float o = bc[t];
        for (int d = 0; d < 64; ++d) o += pooled[d] * Wc[d * 10 + t];
        out[(size_t)g * 10 + t] = o;
    }
}

// ---------------------------------------------------------------------------
extern "C" void kernel_launch(void* const* d_in, const int* in_sizes, int n_in,
                              void* d_out, int out_size, void* d_ws, size_t ws_size,
                              hipStream_t stream) {
    const int*   feat  = (const int*)d_in[0];
    const int*   edges = (const int*)d_in[1];
    const int*   batch = (const int*)d_in[2];
    const float* emb   = (const float*)d_in[3];
    const float* Wl    = (const float*)d_in[4];
    const float* bl    = (const float*)d_in[5];
    const float* Wr    = (const float*)d_in[6];
    const float* br    = (const float*)d_in[7];
    const float* att   = (const float*)d_in[8];
    const float* gb    = (const float*)d_in[9];
    const float* Wc    = (const float*)d_in[10];
    const float* bc    = (const float*)d_in[11];
    float* out = (float*)d_out;

    const int N = in_sizes[2];
    const int E = in_sizes[1] / 2;
    const int G = out_size / 10;

    char* ws = (char*)d_ws;
    size_t off = 0;
    auto alloc = [&](size_t bytes) -> char* {
        char* p = ws + off;
        off = (off + bytes + 255) & ~(size_t)255;
        return p;
    };
    float* x         = (float*)alloc((size_t)N * 64 * 4);
    float* xl        = (float*)alloc((size_t)N * 256 * 4);
    float* xr        = (float*)alloc((size_t)N * 256 * 4);
    int*   counts    = (int*)alloc((size_t)N * 4);
    int*   csr_off   = (int*)alloc((size_t)(N + 8) * 4);
    int*   cursor    = (int*)alloc((size_t)N * 4);
    int*   csr_src   = (int*)alloc((size_t)(E + N + 64) * 4);
    int*   blockSums = (int*)alloc(256 * 4);

    const int* srcv = edges;
    const int* dstv = edges + E;

    // 1) zero counts, fused embed + histogram
    hipMemsetAsync(counts, 0, (size_t)N * 4, stream);
    hipLaunchKernelGGL(embed_kernel, dim3((N + 3) / 4), dim3(256), 0, stream,
                       feat, emb, dstv, counts, x, N, E);

    // 2) CSR by destination (scan_sums folded into finalize)
    int nb = (N + 1023) / 1024;
    hipLaunchKernelGGL(scan_block_kernel, dim3(nb), dim3(256), 0, stream, counts, csr_off, blockSums, N);
    hipLaunchKernelGGL(finalize_kernel, dim3((N + 255) / 256), dim3(256), 0, stream,
                       csr_off, blockSums, cursor, csr_src, N, E + N);
    hipLaunchKernelGGL(scatter_kernel, dim3((E + 255) / 256), dim3(256), 0, stream, srcv, dstv, cursor, csr_src, E);

    // 3) GATv2 layers
    for (int l = 0; l < 3; ++l) {
        hipLaunchKernelGGL(gemm_kernel, dim3((N + 127) / 128, 4), dim3(256), 0, stream,
                           x, Wl + (size_t)l * 64 * 256, Wr + (size_t)l * 64 * 256,
                           bl + l * 256, br + l * 256, xl, xr, N);
        hipLaunchKernelGGL(agg_kernel, dim3((N + 3) / 4), dim3(256), 0, stream,
                           xl, xr, csr_off, csr_src, att + l * 256, gb + l * 64,
                           x, N, (l < 2) ? 1 : 0);
    }

    // 4) pool + classify
    hipLaunchKernelGGL(pool_kernel, dim3(G), dim3(256), 0, stream, x, batch, Wc, bc, out, N, G);
}